// Round 4
// baseline (156.644 us; speedup 1.0000x reference)
//
#include <hip/hip_runtime.h>
#include <hip/hip_cooperative_groups.h>

namespace cg = cooperative_groups;

#define B 2
#define N 4096
#define C 192
#define H 8
#define D 24
#define ROWS 32                 // rows per chunk
#define NCHUNK (B * N / ROWS)   // 256 chunks total
#define PJ 1544                 // per-chunk partial floats: 1536 xw + 8 z

// ws layout (float offsets)
#define PART_OFF 0              // part [NCHUNK][PJ]  = 395264
#define XW_OFF   395264         // xw   [B][PJ]       = 3088

// Single cooperative kernel, 256 blocks x 256 threads (1 block/CU).
// Phase A: per-32-row chunk: build wk in LDS, stage x rows, compute e in LDS,
//          emit 1544 partial floats (1536 e.x sums + 8 e sums) to ws.
// sync
// Phase B: xw[b][j] = sum over 128 chunks of part (8 lanes/output, shuffle-reduce).
// sync
// Phase C: per block: obar[t] = (xw[h].Wv[t])/Z[h]; y = Wproj.obar + bproj;
//          broadcast y into this block's 32 output rows.
__global__ __launch_bounds__(256, 1) void k_fused(const float* __restrict__ x,
                                                  const float* __restrict__ Wqkv,
                                                  const float* __restrict__ Wproj,
                                                  const float* __restrict__ bproj,
                                                  const float* __restrict__ scale,
                                                  float* __restrict__ part,
                                                  float* __restrict__ xw,
                                                  float* __restrict__ out) {
    cg::grid_group grid = cg::this_grid();
    __shared__ __align__(16) float wk[H * 196];
    __shared__ __align__(16) float lx[ROWS * 196];
    __shared__ float le[ROWS * 9];
    __shared__ __align__(16) float lxw[PJ];
    __shared__ __align__(16) float lobar[C];
    __shared__ __align__(16) float ly[C];

    const int tid = threadIdx.x;
    const int blk = blockIdx.x;                 // chunk id

    // ---- Phase A ----
    // wk[h][c] = sum_d Wqkv[(C+h*D+d)*C + c]  (Wqkv slice L2-hot across blocks)
    for (int i = tid; i < H * C; i += 256) {
        const int h = i / C, c = i - h * C;
        const float* wr = Wqkv + (size_t)(C + h * D) * C + c;
        float s = 0.f;
        #pragma unroll
        for (int d = 0; d < D; ++d) s += wr[d * C];
        wk[h * 196 + c] = s;
    }
    // stage 32 rows of x (coalesced float4), padded LDS rows
    const float4* xb = (const float4*)(x + (size_t)blk * ROWS * C);
    #pragma unroll
    for (int k = 0; k < 6; ++k) {
        const int f4 = tid + k * 256;           // 0..1535
        const int r = f4 / 48, c4 = f4 - r * 48;
        *(float4*)&lx[r * 196 + c4 * 4] = xb[f4];
    }
    __syncthreads();

    // e: thread -> (r = tid>>3, h = tid&7)
    {
        const int r = tid >> 3, h = tid & 7;
        const float4* xr = (const float4*)&lx[r * 196];
        const float4* wh = (const float4*)&wk[h * 196];
        float acc = 0.f;
        #pragma unroll 8
        for (int c4 = 0; c4 < 48; ++c4) {
            float4 a = xr[c4], w = wh[c4];
            acc += a.x * w.x + a.y * w.y + a.z * w.z + a.w * w.w;
        }
        le[r * 9 + h] = __expf(acc * scale[0]);
    }
    __syncthreads();

    // partials: thread -> (h = tid>>5, c = (tid&31) + 32j)
    {
        const int h = tid >> 5, c0 = tid & 31;
        float acc[6] = {};
        float zacc = 0.f;
        for (int r = 0; r < ROWS; ++r) {
            const float e = le[r * 9 + h];
            if (c0 == 0) zacc += e;
            #pragma unroll
            for (int j = 0; j < 6; ++j) acc[j] += e * lx[r * 196 + c0 + 32 * j];
        }
        float* pb = part + (size_t)blk * PJ;
        #pragma unroll
        for (int j = 0; j < 6; ++j) pb[h * C + c0 + 32 * j] = acc[j];
        if (c0 == 0) pb[1536 + h] = zacc;
    }

    grid.sync();

    // ---- Phase B ---- 8 lanes per output, 16 chunk-strided loads per lane
    {
        const int gid = blk * 256 + tid;
        const int g = gid >> 3, li = gid & 7;   // g: output id, li: lane in group
        if (g < B * PJ) {
            const int b = g / PJ, j = g - b * PJ;
            const float* p = part + (size_t)(b * 128 + li) * PJ + j;
            float s = 0.f;
            #pragma unroll
            for (int k = 0; k < 16; ++k) s += p[(size_t)(8 * k) * PJ];
            s += __shfl_xor(s, 1);
            s += __shfl_xor(s, 2);
            s += __shfl_xor(s, 4);
            if (li == 0) xw[g] = s;
        }
    }

    grid.sync();

    // ---- Phase C ----
    const int b = blk >> 7;
    for (int i = tid; i < PJ; i += 256) lxw[i] = xw[b * PJ + i];
    __syncthreads();

    if (tid < C) {
        const int h = tid / D;
        const float4* wv = (const float4*)(Wqkv + (size_t)(2 * C + tid) * C);
        const float4* xh = (const float4*)&lxw[h * C];
        float s = 0.f;
        #pragma unroll 8
        for (int c4 = 0; c4 < 48; ++c4) {
            float4 a = wv[c4], w = xh[c4];
            s += a.x * w.x + a.y * w.y + a.z * w.z + a.w * w.w;
        }
        lobar[tid] = s / lxw[1536 + h];
    }
    __syncthreads();

    if (tid < C) {
        const float4* wp = (const float4*)(Wproj + (size_t)tid * C);
        const float4* ob = (const float4*)lobar;
        float s = bproj[tid];
        #pragma unroll 8
        for (int c4 = 0; c4 < 48; ++c4) {
            float4 a = wp[c4], w = ob[c4];
            s += a.x * w.x + a.y * w.y + a.z * w.z + a.w * w.w;
        }
        ly[tid] = s;
    }
    __syncthreads();

    float4* o4 = (float4*)out + (size_t)blk * 1536;
    const float4* ly4 = (const float4*)ly;
    #pragma unroll
    for (int k = 0; k < 6; ++k) {
        const int f4 = tid + k * 256;
        o4[f4] = ly4[f4 % 48];
    }
}

extern "C" void kernel_launch(void* const* d_in, const int* in_sizes, int n_in,
                              void* d_out, int out_size, void* d_ws, size_t ws_size,
                              hipStream_t stream) {
    const float* x     = (const float*)d_in[0];
    const float* Wqkv  = (const float*)d_in[1];
    const float* Wproj = (const float*)d_in[2];
    const float* bproj = (const float*)d_in[3];
    const float* scale = (const float*)d_in[4];
    float* out  = (float*)d_out;
    float* ws   = (float*)d_ws;
    float* part = ws + PART_OFF;
    float* xw   = ws + XW_OFF;

    void* args[] = {(void*)&x, (void*)&Wqkv, (void*)&Wproj, (void*)&bproj,
                    (void*)&scale, (void*)&part, (void*)&xw, (void*)&out};
    hipLaunchCooperativeKernel((const void*)k_fused, dim3(NCHUNK), dim3(256),
                               args, 0, stream);
}

// Round 5
// 85.391 us; speedup vs baseline: 1.8344x; 1.8344x over previous
//
#include <hip/hip_runtime.h>

#define B 2
#define N 4096
#define C 192
#define H 8
#define D 24
#define ROWS 32                 // rows per chunk
#define NCHUNK (B * N / ROWS)   // 256 chunks total
#define PJ 1544                 // per-chunk partial floats: 1536 xw + 8 z

// ws layout (float offsets)
#define PART_OFF 0              // part [NCHUNK][PJ]  = 395264
#define XW_OFF   395264         // xw   [B][PJ]       = 3088

// A: one block per 32-row chunk.
//   wk[h][c] = sum_d Wqkv[(C+h*D+d)*C + c]           (in LDS, padded stride 196)
//   e[r][h]  = exp(scale * dot(x_row, wk[h]))        (in LDS only)
//   part[chunk][h*C+c]   = sum_r e[r][h] * x[r][c]
//   part[chunk][1536+h]  = sum_r e[r][h]
__global__ __launch_bounds__(256) void kA(const float* __restrict__ x,
                                          const float* __restrict__ Wqkv,
                                          const float* __restrict__ scale,
                                          float* __restrict__ part) {
    __shared__ __align__(16) float wk[H * 196];
    __shared__ __align__(16) float lx[ROWS * 196];
    __shared__ float le[ROWS * 9];
    const int tid = threadIdx.x;
    const int blk = blockIdx.x;                 // chunk id

    // wk (each block builds its own copy; Wqkv slice is L2-hot)
    for (int i = tid; i < H * C; i += 256) {
        const int h = i / C, c = i - h * C;
        const float* wr = Wqkv + (size_t)(C + h * D) * C + c;
        float s = 0.f;
        #pragma unroll
        for (int d = 0; d < D; ++d) s += wr[d * C];
        wk[h * 196 + c] = s;
    }
    // stage 32 rows of x (coalesced float4), padded LDS rows
    const float4* xb = (const float4*)(x + (size_t)blk * ROWS * C);
    #pragma unroll
    for (int k = 0; k < 6; ++k) {
        const int f4 = tid + k * 256;           // 0..1535
        const int r = f4 / 48, c4 = f4 - r * 48;
        *(float4*)&lx[r * 196 + c4 * 4] = xb[f4];
    }
    __syncthreads();

    // e: thread -> (r = tid>>3, h = tid&7)
    {
        const int r = tid >> 3, h = tid & 7;
        const float4* xr = (const float4*)&lx[r * 196];
        const float4* wh = (const float4*)&wk[h * 196];
        float acc = 0.f;
        #pragma unroll 8
        for (int c4 = 0; c4 < 48; ++c4) {
            float4 a = xr[c4], w = wh[c4];
            acc += a.x * w.x + a.y * w.y + a.z * w.z + a.w * w.w;
        }
        le[r * 9 + h] = __expf(acc * scale[0]);
    }
    __syncthreads();

    // partials: thread -> (h = tid>>5, c = (tid&31) + 32j)
    const int h = tid >> 5, c0 = tid & 31;
    float acc[6] = {};
    float zacc = 0.f;
    for (int r = 0; r < ROWS; ++r) {
        const float e = le[r * 9 + h];
        if (c0 == 0) zacc += e;
        #pragma unroll
        for (int j = 0; j < 6; ++j) acc[j] += e * lx[r * 196 + c0 + 32 * j];
    }
    float* pb = part + (size_t)blk * PJ;
    #pragma unroll
    for (int j = 0; j < 6; ++j) pb[h * C + c0 + 32 * j] = acc[j];
    if (c0 == 0) pb[1536 + h] = zacc;
}

// B: xw[b][j] = sum_{ch<128} part[b*128+ch][j]
// 8 lanes per output: 16 independent strided loads each, then shuffle-reduce.
__global__ __launch_bounds__(256) void kB(const float* __restrict__ part,
                                          float* __restrict__ xw) {
    const int gid = blockIdx.x * 256 + threadIdx.x;
    const int g = gid >> 3, li = gid & 7;       // g: output id, li: lane in group
    if (g >= B * PJ) return;
    const int b = g / PJ, j = g - b * PJ;
    const float* p = part + (size_t)(b * 128 + li) * PJ + j;
    float s = 0.f;
    #pragma unroll
    for (int k = 0; k < 16; ++k) s += p[(size_t)(8 * k) * PJ];
    s += __shfl_xor(s, 1);
    s += __shfl_xor(s, 2);
    s += __shfl_xor(s, 4);
    if (li == 0) xw[g] = s;
}

// C: per chunk-block: obar[t] = (xw[b][h*C:] . Wv[t]) / Z[h];
//    y[o] = bproj[o] + obar . Wproj[o];  out rows <- y
__global__ __launch_bounds__(256) void kC(const float* __restrict__ Wqkv,
                                          const float* __restrict__ Wproj,
                                          const float* __restrict__ bproj,
                                          const float* __restrict__ xw,
                                          float* __restrict__ out) {
    __shared__ __align__(16) float lxw[PJ];
    __shared__ __align__(16) float lobar[C];
    __shared__ __align__(16) float ly[C];
    const int tid = threadIdx.x;
    const int blk = blockIdx.x;                 // chunk id
    const int b = blk >> 7;

    for (int i = tid; i < PJ; i += 256) lxw[i] = xw[b * PJ + i];
    __syncthreads();

    if (tid < C) {
        const int h = tid / D;
        const float4* wv = (const float4*)(Wqkv + (size_t)(2 * C + tid) * C);
        const float4* xh = (const float4*)&lxw[h * C];
        float s = 0.f;
        #pragma unroll 8
        for (int c4 = 0; c4 < 48; ++c4) {
            float4 a = wv[c4], w = xh[c4];
            s += a.x * w.x + a.y * w.y + a.z * w.z + a.w * w.w;
        }
        lobar[tid] = s / lxw[1536 + h];
    }
    __syncthreads();

    if (tid < C) {
        const float4* wp = (const float4*)(Wproj + (size_t)tid * C);
        const float4* ob = (const float4*)lobar;
        float s = bproj[tid];
        #pragma unroll 8
        for (int c4 = 0; c4 < 48; ++c4) {
            float4 a = wp[c4], w = ob[c4];
            s += a.x * w.x + a.y * w.y + a.z * w.z + a.w * w.w;
        }
        ly[tid] = s;
    }
    __syncthreads();

    float4* o4 = (float4*)out + (size_t)blk * 1536;
    const float4* ly4 = (const float4*)ly;
    #pragma unroll
    for (int k = 0; k < 6; ++k) {
        const int f4 = tid + k * 256;
        o4[f4] = ly4[f4 % 48];
    }
}

extern "C" void kernel_launch(void* const* d_in, const int* in_sizes, int n_in,
                              void* d_out, int out_size, void* d_ws, size_t ws_size,
                              hipStream_t stream) {
    const float* x     = (const float*)d_in[0];
    const float* Wqkv  = (const float*)d_in[1];
    const float* Wproj = (const float*)d_in[2];
    const float* bproj = (const float*)d_in[3];
    const float* scale = (const float*)d_in[4];
    float* out  = (float*)d_out;
    float* ws   = (float*)d_ws;
    float* part = ws + PART_OFF;
    float* xw   = ws + XW_OFF;

    kA<<<NCHUNK, 256, 0, stream>>>(x, Wqkv, scale, part);
    kB<<<(B * PJ * 8 + 255) / 256, 256, 0, stream>>>(part, xw);
    kC<<<NCHUNK, 256, 0, stream>>>(Wqkv, Wproj, bproj, xw, out);
}